// Round 5
// baseline (107.667 us; speedup 1.0000x reference)
//
#include <hip/hip_runtime.h>

// Viterbi trellis quantizer: S=1024 states, K=2 (4 preds), CHUNK=4,
// T=64 steps/chain, B=4096 chains (16x16 blocks of a 1024^2 array).
//
// R4 forensics: with 16 codebook rows/lane (80 regs) the allocator ALWAYS
// keeps arch VGPRs at the 64-reg tier and shunts the codebook into AGPRs
// (R4: VGPR=60, no spill bytes, ~255 inst/step vs ~130 in source = ~80
// v_accvgpr_read per step). Fix: make the working set truly fit 64 VGPRs.
//
// New mapping: TWO waves per chain (128 lanes). Lane L owns state-groups
// p = 2L, 2L+1 -> 8 codebook rows (32 regs) + h (8 regs). Cross-wave M
// exchange via ping-pong LDS buffers + one __syncthreads per step.
// beta-form: beta_new[s] = max_j M_prev[(s>>2)+64j... ] + (cb[s]·x + h[s]),
// M_t[p] = max_j beta_t[p+256j]; backpointer J[t][p] = argmax j (2 bits),
// two steps packed per byte.

#define COLS      1024
#define T_STEPS   64
#define REC_SIZE  (1024 * 1024)

__global__ __launch_bounds__(128) void viterbi_q(
    const float* __restrict__ arr,
    const float* __restrict__ cbook,
    float* __restrict__ out)
{
    const int tid   = threadIdx.x;   // 0..127 = chain-lane L
    const int wid   = tid >> 6;      // wave id within chain
    const int lane  = tid & 63;
    const int chain = blockIdx.x;    // 0..4095
    const int rb    = chain >> 6;    // block-row
    const int cbc   = chain & 63;    // block-col

    __shared__ __align__(16) float tile[256];    // x chunks
    __shared__ __align__(16) float Mbuf[512];    // ping-pong grouped-max M
    __shared__ unsigned char J[32 * 128];        // 2 steps/byte backpointers
    __shared__ int   st_lds[64];                 // traced-back states
    __shared__ float redv[2];
    __shared__ int   reds[2];

    // ---- stage the 16x16 tile (wave 0) ----
    if (tid < 64) {
        const int r  = tid >> 2;
        const int c4 = (tid & 3) << 2;
        float4 v = *(const float4*)(arr + (rb * 16 + r) * COLS + cbc * 16 + c4);
        *(float4*)&tile[tid << 2] = v;
    }
    // M(-1) = 0 in buffer 0: iter t=0 then yields beta0 = cb·x0 + h exactly.
    *(float2*)&Mbuf[tid << 1] = make_float2(0.f, 0.f);

    // ---- codebook rows for this lane's 8 states: s = 2L + c + 256j ----
    float4 a[8];   // raw codebook row
    float  h[8];   // -||row||^2 / 2
    #pragma unroll
    for (int j = 0; j < 4; ++j) {
        #pragma unroll
        for (int c = 0; c < 2; ++c) {
            const int row = (tid << 1) + c + (j << 8);
            float4 v = *(const float4*)(cbook + row * 4);
            a[j * 2 + c] = v;
            h[j * 2 + c] = -0.5f * (v.x * v.x + v.y * v.y +
                                    v.z * v.z + v.w * v.w);
        }
    }
    __syncthreads();

    const int pg = tid >> 1;    // shared predecessor group (both c)
    unsigned nib_hold = 0;

    // ---- forward recursion, t = 0..62: J[t] = winning group member ----
    #pragma unroll 1
    for (int t = 0; t < T_STEPS - 1; ++t) {
        const float* __restrict__ Mr = Mbuf + ((t & 1) << 8);
        float* __restrict__       Mw = Mbuf + (((t + 1) & 1) << 8);

        float4 xt = *(const float4*)&tile[t << 2];   // wave-uniform broadcast
        float mj[4];
        #pragma unroll
        for (int j = 0; j < 4; ++j)
            mj[j] = Mr[pg + 64 * j];

        float nm[2];
        unsigned bp = 0;
        #pragma unroll
        for (int c = 0; c < 2; ++c) {
            float cand[4];
            #pragma unroll
            for (int j = 0; j < 4; ++j) {
                const float4 av = a[j * 2 + c];
                float acc = fmaf(av.x, xt.x, h[j * 2 + c]);
                acc = fmaf(av.y, xt.y, acc);
                acc = fmaf(av.z, xt.z, acc);
                acc = fmaf(av.w, xt.w, acc);
                cand[c ? 4 + j - 4 : j] = acc + mj[j];
                cand[j] = acc + mj[j];
            }
            const float v = fmaxf(fmaxf(cand[0], cand[1]),
                                  fmaxf(cand[2], cand[3]));
            // first-max index (== reference first-min over alpha)
            const int j = (cand[0] == v) ? 0
                        : (cand[1] == v) ? 1
                        : (cand[2] == v) ? 2 : 3;
            nm[c] = v;
            bp |= (unsigned)j << (2 * c);
        }
        *(float2*)&Mw[tid << 1] = make_float2(nm[0], nm[1]);
        if (t & 1) J[(t >> 1) * 128 + tid] = (unsigned char)(nib_hold | (bp << 4));
        else       nib_hold = bp;
        __syncthreads();
    }
    J[31 * 128 + tid] = (unsigned char)nib_hold;   // t=62 (even, held)

    // ---- final step t = 63: full argmax over beta_63[0..1023] ----
    {
        const float* __restrict__ Mr = Mbuf + ((63 & 1) << 8);
        float4 xt = *(const float4*)&tile[63 << 2];
        float mj[4];
        #pragma unroll
        for (int j = 0; j < 4; ++j)
            mj[j] = Mr[pg + 64 * j];

        float bv = -3.4e38f;
        int   bs = 0;
        #pragma unroll
        for (int j = 0; j < 4; ++j) {        // s ascends with (j, c): first-max
            #pragma unroll
            for (int c = 0; c < 2; ++c) {
                const float4 av = a[j * 2 + c];
                float acc = fmaf(av.x, xt.x, h[j * 2 + c]);
                acc = fmaf(av.y, xt.y, acc);
                acc = fmaf(av.z, xt.z, acc);
                acc = fmaf(av.w, xt.w, acc);
                acc += mj[j];
                if (acc > bv) { bv = acc; bs = (tid << 1) + c + (j << 8); }
            }
        }
        // lexicographic (value desc, state asc) butterfly within the wave
        #pragma unroll
        for (int off = 32; off > 0; off >>= 1) {
            const float ov = __shfl_xor(bv, off, 64);
            const int   os = __shfl_xor(bs, off, 64);
            if (ov > bv || (ov == bv && os < bs)) { bv = ov; bs = os; }
        }
        if (lane == 0) { redv[wid] = bv; reds[wid] = bs; }
    }
    __syncthreads();   // also covers the J[31] writes above

    // ---- traceback (serial, thread 0) ----
    if (tid == 0) {
        float bv = redv[0]; int bs = reds[0];
        if (redv[1] > bv || (redv[1] == bv && reds[1] < bs)) {
            bv = redv[1]; bs = reds[1];
        }
        int s = bs;
        st_lds[T_STEPS - 1] = s;
        for (int i = T_STEPS - 2; i >= 0; --i) {
            const int p = s >> 2;
            const unsigned byte = J[(i >> 1) * 128 + (p >> 1)];
            const int j = (byte >> (((i & 1) << 2) + ((p & 1) << 1))) & 3;
            s = p + (j << 8);
            st_lds[i] = s;
        }
    }
    __syncthreads();

    // ---- outputs ----
    if (tid < 64) {
        // rec: lane t covers elements 4t..4t+3 -> row t>>2, cols 4*(t&3)..+3
        const int st = st_lds[tid];
        const float4 v = *(const float4*)(cbook + st * 4);
        const int r  = tid >> 2;
        const int c4 = (tid & 3) << 2;
        *(float4*)(out + (rb * 16 + r) * COLS + cbc * 16 + c4) = v;
    } else {
        // states flat: REC_SIZE + chain*64 + t (stored as float values)
        const int t = tid - 64;
        out[REC_SIZE + chain * 64 + t] = (float)st_lds[t];
    }
}

extern "C" void kernel_launch(void* const* d_in, const int* in_sizes, int n_in,
                              void* d_out, int out_size, void* d_ws, size_t ws_size,
                              hipStream_t stream)
{
    const float* arr   = (const float*)d_in[0];
    const float* cbook = (const float*)d_in[1];
    float* out = (float*)d_out;
    // one chain per 128-thread block (2 waves/chain), 4096 blocks
    viterbi_q<<<dim3(4096), dim3(128), 0, stream>>>(arr, cbook, out);
}